// Round 4
// baseline (1847.961 us; speedup 1.0000x reference)
//
#include <hip/hip_runtime.h>

// Problem constants
#define N_NODES 100000
#define HDIM    64
#define R_REL   3
#define E_EDGES 800000
#define L_EDGES 200000
#define NT      (N_NODES/16)   // 6250 node tiles of 16
#define DB      512            // dense blocks (per relation): 2048 waves
#define GB      1024           // gru blocks (per relation)
#define ABPR    391            // att blocks per relation

typedef short s16x8 __attribute__((ext_vector_type(8)));
typedef float f32x4 __attribute__((ext_vector_type(4)));
typedef unsigned short u16;

__device__ __forceinline__ u16 f2bf(float f){
    union { float f; unsigned int i; } v; v.f = f;
    unsigned int u = v.i + 0x7FFFu + ((v.i >> 16) & 1u);   // RNE
    return (u16)(u >> 16);
}
__device__ __forceinline__ s16x8 packbf(float4 a, float4 b){
    s16x8 r;
    r[0]=(short)f2bf(a.x); r[1]=(short)f2bf(a.y); r[2]=(short)f2bf(a.z); r[3]=(short)f2bf(a.w);
    r[4]=(short)f2bf(b.x); r[5]=(short)f2bf(b.y); r[6]=(short)f2bf(b.z); r[7]=(short)f2bf(b.w);
    return r;
}
__device__ __forceinline__ s16x8 ldpack(const float* p){   // 8 consecutive f32 -> bf16x8
    return packbf(*(const float4*)p, *(const float4*)(p + 4));
}
__device__ __forceinline__ f32x4 mfma16(s16x8 a, s16x8 b, f32x4 c){
    return __builtin_amdgcn_mfma_f32_16x16x32_bf16(a, b, c, 0, 0, 0);
}
__device__ __forceinline__ float fsigm(float x){
    x = fmaxf(-30.f, fminf(30.f, x));
    return 1.f/(1.f + __expf(-x));
}
__device__ __forceinline__ float ftanh(float x){
    x = fminf(15.f, fmaxf(-15.f, x));
    float e = __expf(2.f*x);
    return (e-1.f)/(e+1.f);
}

// ---- scatter (one relation): agg[dst][f] += xin[src][f], agg pre-zeroed ----
__global__ __launch_bounds__(256) void k_scatter(const int* __restrict__ ei_r,
        const float* __restrict__ xin, float* __restrict__ agg)
{
    int gw = blockIdx.x*4 + (threadIdx.x >> 6);   // edge id, grid = E/4
    int lane = threadIdx.x & 63;
    int src = ei_r[gw];
    int dst = ei_r[E_EDGES + gw];
    float v = xin[(size_t)src*64 + lane];
    unsafeAtomicAdd(agg + (size_t)dst*64 + lane, v);
}

// ---- dense (one relation): h = relu(agg@Wr.T + br + xin@Wo.T) (f32 out); re-zeroes agg ----
__global__ __launch_bounds__(256) void k_dense(float* agg,
        const float* __restrict__ xin, const float* __restrict__ Wr,
        const float* __restrict__ br, const float* __restrict__ Wo,
        float* __restrict__ hbuf)
{
    int w = threadIdx.x >> 6, lane = threadIdx.x & 63;
    int col = lane & 15, quad = lane >> 4, k0 = quad*8;

    s16x8 fr[4][2], fo[4][2];
    float bias[4];
    #pragma unroll
    for (int c = 0; c < 4; ++c){
        int m = c*16 + col;
        fr[c][0] = ldpack(Wr + m*64 + k0);
        fr[c][1] = ldpack(Wr + m*64 + 32 + k0);
        fo[c][0] = ldpack(Wo + m*64 + k0);
        fo[c][1] = ldpack(Wo + m*64 + 32 + k0);
        bias[c]  = br[m];
    }
    int wid = blockIdx.x*4 + w;
    for (int t = wid; t < NT; t += DB*4){
        int node = t*16 + col;
        float* arow = agg + (size_t)node*64;
        s16x8 a1h0 = ldpack(arow + k0);
        s16x8 a1h1 = ldpack(arow + 32 + k0);
        // re-zero agg for the next relation's scatter (same-address load->store
        // dependence keeps ordering)
        float4 zz = {0.f,0.f,0.f,0.f};
        *(float4*)(arow + k0)      = zz;
        *(float4*)(arow + k0 + 4)  = zz;
        *(float4*)(arow + 32 + k0) = zz;
        *(float4*)(arow + 36 + k0) = zz;

        s16x8 a2h0 = ldpack(xin + (size_t)node*64 + k0);
        s16x8 a2h1 = ldpack(xin + (size_t)node*64 + 32 + k0);
        #pragma unroll
        for (int c = 0; c < 4; ++c){
            f32x4 acc = {0.f,0.f,0.f,0.f};
            acc = mfma16(a1h0, fr[c][0], acc);
            acc = mfma16(a1h1, fr[c][1], acc);
            acc = mfma16(a2h0, fo[c][0], acc);
            acc = mfma16(a2h1, fo[c][1], acc);
            #pragma unroll
            for (int i = 0; i < 4; ++i){
                int row = t*16 + quad*4 + i;
                float v = acc[i] + bias[c];
                hbuf[(size_t)row*64 + c*16 + col] = v > 0.f ? v : 0.f;
            }
        }
    }
}

// ---- GRU (one relation), all f32. hbuf MAY ALIAS cur: barrier after loads.
// All 4 waves of a block work on the SAME tile t; wave w owns cols w*16..w*16+15.
__global__ __launch_bounds__(256) void k_gru(const float* hbuf, const float* past,
        const float* __restrict__ Wi, const float* __restrict__ Wh,
        const float* __restrict__ bi_, const float* __restrict__ bh_, float* cur)
{
    int w = threadIdx.x >> 6, lane = threadIdx.x & 63;
    int col = lane & 15, quad = lane >> 4, k0 = quad*8;

    s16x8 fwi[3][2], fwh[3][2];
    float vbi[3], vbh[3];
    #pragma unroll
    for (int g = 0; g < 3; ++g){
        int m = g*64 + w*16 + col;
        fwi[g][0] = ldpack(Wi + m*64 + k0);
        fwi[g][1] = ldpack(Wi + m*64 + 32 + k0);
        fwh[g][0] = ldpack(Wh + m*64 + k0);
        fwh[g][1] = ldpack(Wh + m*64 + 32 + k0);
        vbi[g] = bi_[m]; vbh[g] = bh_[m];
    }
    int j = w*16 + col;
    for (int t = blockIdx.x; t < NT; t += GB){
        int node = t*16 + col;
        const float* hrow = hbuf + (size_t)node*64;
        const float* prow = past + (size_t)node*64;
        s16x8 ah0 = ldpack(hrow + k0);
        s16x8 ah1 = ldpack(hrow + 32 + k0);
        s16x8 ap0 = ldpack(prow + k0);
        s16x8 ap1 = ldpack(prow + 32 + k0);
        float pv[4];
        #pragma unroll
        for (int i = 0; i < 4; ++i)
            pv[i] = past[(size_t)(t*16 + quad*4 + i)*64 + j];
        // all waves must finish reading h[t] before any wave overwrites cur[t]
        // (__syncthreads drains vmcnt -> loads are in registers)
        __syncthreads();
        f32x4 gi[3], gh[3];
        #pragma unroll
        for (int g = 0; g < 3; ++g){
            f32x4 z0 = {0.f,0.f,0.f,0.f};
            gi[g] = mfma16(ah1, fwi[g][1], mfma16(ah0, fwi[g][0], z0));
            gh[g] = mfma16(ap1, fwh[g][1], mfma16(ap0, fwh[g][0], z0));
        }
        #pragma unroll
        for (int i = 0; i < 4; ++i){
            int row = t*16 + quad*4 + i;
            float ir = gi[0][i]+vbi[0], iz = gi[1][i]+vbi[1], in_ = gi[2][i]+vbi[2];
            float hr = gh[0][i]+vbh[0], hz = gh[1][i]+vbh[1], hn = gh[2][i]+vbh[2];
            float rg = fsigm(ir + hr);
            float zg = fsigm(iz + hz);
            float ng = ftanh(in_ + rg*hn);
            cur[(size_t)row*64 + j] = (1.f - zg)*ng + zg*pv[i];
        }
    }
}

// ---- attention score (all rels): scoreOut[r] += sum_n sum_j q[j]*tanh(cur@kW.T+kb)_nj ----
__global__ __launch_bounds__(256) void k_att(const float* __restrict__ cur,
        const float* __restrict__ kW, const float* __restrict__ kb,
        const float* __restrict__ q, float* __restrict__ scoreOut)
{
    int r  = blockIdx.x / ABPR;
    int bi = blockIdx.x % ABPR;
    int w = threadIdx.x >> 6, lane = threadIdx.x & 63;
    int col = lane & 15, quad = lane >> 4, k0 = quad*8;

    s16x8 fk[4][2];
    float vkb[4], vq[4];
    #pragma unroll
    for (int c = 0; c < 4; ++c){
        int m = c*16 + col;
        fk[c][0] = ldpack(kW + m*64 + k0);
        fk[c][1] = ldpack(kW + m*64 + 32 + k0);
        vkb[c] = kb[m]; vq[c] = q[m];
    }
    float p = 0.f;
    int wid = bi*4 + w;
    for (int t = wid; t < NT; t += ABPR*4){
        int node = t*16 + col;
        const float* crow = cur + ((size_t)r*N_NODES + node)*64;
        s16x8 a0 = ldpack(crow + k0);
        s16x8 a1 = ldpack(crow + 32 + k0);
        #pragma unroll
        for (int c = 0; c < 4; ++c){
            f32x4 acc = {0.f,0.f,0.f,0.f};
            acc = mfma16(a1, fk[c][1], mfma16(a0, fk[c][0], acc));
            #pragma unroll
            for (int i = 0; i < 4; ++i)
                p += ftanh(acc[i] + vkb[c]) * vq[c];
        }
    }
    #pragma unroll
    for (int o = 32; o; o >>= 1) p += __shfl_xor(p, o, 64);
    if (lane == 0) unsafeAtomicAdd(scoreOut + r, p);
}

// ---- combine1: aggsem(f32) = sum_r softmax(score)[r] * cur[r] ----
__global__ __launch_bounds__(256) void k_combine1(const float* __restrict__ scoreS,
        const float* __restrict__ cur, float* __restrict__ aggsem)
{
    float s0 = scoreS[0]*(1.f/N_NODES), s1 = scoreS[1]*(1.f/N_NODES), s2 = scoreS[2]*(1.f/N_NODES);
    float mx = fmaxf(s0, fmaxf(s1, s2));
    float e0 = __expf(s0-mx), e1 = __expf(s1-mx), e2 = __expf(s2-mx);
    float inv = 1.f/(e0+e1+e2);
    float a0 = e0*inv, a1 = e1*inv, a2 = e2*inv;

    size_t idx = (size_t)blockIdx.x*blockDim.x + threadIdx.x;   // one thread = 4 elems
    const size_t S = (size_t)N_NODES*64;
    float4 v0 = *(const float4*)(cur + idx*4);
    float4 v1 = *(const float4*)(cur + S + idx*4);
    float4 v2 = *(const float4*)(cur + 2*S + idx*4);
    float4 o;
    o.x = a0*v0.x + a1*v1.x + a2*v2.x;
    o.y = a0*v0.y + a1*v1.y + a2*v2.y;
    o.z = a0*v0.z + a1*v1.z + a2*v2.z;
    o.w = a0*v0.w + a1*v1.w + a2*v2.w;
    *(float4*)(aggsem + idx*4) = o;
}

// ---- combine2 + z: z[n] = (sum_r attn[r]*cur2[r][n]) @ postW.T + postb ----
__global__ __launch_bounds__(256) void k_combine2z(const float* __restrict__ scoreS,
        const float* __restrict__ cur2, const float* __restrict__ postW,
        const float* __restrict__ postb, float* __restrict__ z)
{
    float s0 = scoreS[0]*(1.f/N_NODES), s1 = scoreS[1]*(1.f/N_NODES), s2 = scoreS[2]*(1.f/N_NODES);
    float mx = fmaxf(s0, fmaxf(s1, s2));
    float e0 = __expf(s0-mx), e1 = __expf(s1-mx), e2 = __expf(s2-mx);
    float inv = 1.f/(e0+e1+e2);
    float a0 = e0*inv, a1 = e1*inv, a2 = e2*inv;

    int wid = (int)((blockIdx.x*blockDim.x + threadIdx.x) >> 6);  // node
    int lane = threadIdx.x & 63;
    const size_t S = (size_t)N_NODES*64;
    size_t o = (size_t)wid*64 + lane;
    float v = a0*cur2[o] + a1*cur2[S + o] + a2*cur2[2*S + o];
    float p0 = v * postW[lane];
    float p1 = v * postW[64 + lane];
    #pragma unroll
    for (int s = 32; s; s >>= 1){ p0 += __shfl_xor(p0, s, 64); p1 += __shfl_xor(p1, s, 64); }
    if (lane == 0){
        z[(size_t)wid*2]     = p0 + postb[0];
        z[(size_t)wid*2 + 1] = p1 + postb[1];
    }
}

// ---- final edge scores (f32 out) ----
__global__ __launch_bounds__(256) void k_score(const int* __restrict__ eli,
        const float* __restrict__ z, const float* __restrict__ rel,
        float* __restrict__ out)
{
    int tid = blockIdx.x*blockDim.x + threadIdx.x;
    if (tid >= R_REL*L_EDGES) return;
    int r = tid < L_EDGES ? 0 : (tid < 2*L_EDGES ? 1 : 2);
    int l = tid - r*L_EDGES;
    int hn = eli[(size_t)r*2*L_EDGES + l];
    int tn = eli[(size_t)r*2*L_EDGES + L_EDGES + l];
    float hr = z[(size_t)hn*2], hi = z[(size_t)hn*2+1];
    float tr = z[(size_t)tn*2], ti = z[(size_t)tn*2+1];
    float rr = rel[2*r], ri = rel[2*r+1];
    out[tid] = hr*rr*tr + hi*rr*ti + hr*ri*ti - hi*ri*tr;
}

extern "C" void kernel_launch(void* const* d_in, const int* in_sizes, int n_in,
                              void* d_out, int out_size, void* d_ws, size_t ws_size,
                              hipStream_t stream)
{
    const float* x      = (const float*)d_in[0];
    const int*   ei     = (const int*)d_in[1];
    const int*   eli    = (const int*)d_in[2];
    const float* past1  = (const float*)d_in[3];
    const float* past2  = (const float*)d_in[4];
    const float* W1rel  = (const float*)d_in[5];
    const float* b1rel  = (const float*)d_in[6];
    const float* W1root = (const float*)d_in[7];
    const float* g1Wi   = (const float*)d_in[8];
    const float* g1Wh   = (const float*)d_in[9];
    const float* g1bi   = (const float*)d_in[10];
    const float* g1bh   = (const float*)d_in[11];
    const float* k1W    = (const float*)d_in[12];
    const float* k1b    = (const float*)d_in[13];
    const float* q1     = (const float*)d_in[14];
    const float* W2rel  = (const float*)d_in[15];
    const float* b2rel  = (const float*)d_in[16];
    const float* W2root = (const float*)d_in[17];
    const float* g2Wi   = (const float*)d_in[18];
    const float* g2Wh   = (const float*)d_in[19];
    const float* g2bi   = (const float*)d_in[20];
    const float* g2bh   = (const float*)d_in[21];
    const float* k2W    = (const float*)d_in[22];
    const float* k2b    = (const float*)d_in[23];
    const float* q2     = (const float*)d_in[24];
    const float* postW  = (const float*)d_in[25];
    const float* postb  = (const float*)d_in[26];
    const float* rel    = (const float*)d_in[27];

    // ---- workspace layout (52.0 MB total, front-loaded) ----
    char* ws = (char*)d_ws;
    float* scoreS  = (float*)ws;                               // 128 B
    float* z       = (float*)(ws + 128);                       // N*2 f32 = 800,000 B
    float* aggsem  = (float*)(ws + 800128);                    // N*64 f32 = 25.6 MB
    float* agg     = (float*)(ws + 26400128);                  // N*64 f32 = 25.6 MB
    const size_t WS_NEED = 26400128 + (size_t)N_NODES*64*4;    // 52,000,128 B
    if (ws_size < WS_NEED) return;   // diagnostic: finite 0.357 absmax if ws too small

    // outputs are FLOAT32: scores | cur1 | cur2
    float* out  = (float*)d_out;
    float* cur1 = out + 600000;
    float* cur2 = cur1 + (size_t)R_REL*N_NODES*64;

    hipMemsetAsync(scoreS, 0, 128, stream);
    hipMemsetAsync(agg, 0, (size_t)N_NODES*64*4, stream);

    const size_t RS = (size_t)N_NODES*64;   // per-relation slice (elems)

    // ---- layer 1 (h staged f32 in cur2 slot r — free, real cur2 written later) ----
    for (int r = 0; r < R_REL; ++r){
        k_scatter<<<E_EDGES/4, 256, 0, stream>>>(ei + (size_t)r*2*E_EDGES, x, agg);
        k_dense<<<DB, 256, 0, stream>>>(agg, x, W1rel + r*4096, b1rel + r*64,
                                        W1root + r*4096, cur2 + r*RS);
        k_gru<<<GB, 256, 0, stream>>>(cur2 + r*RS, past1 + r*RS,
                                      g1Wi, g1Wh, g1bi, g1bh, cur1 + r*RS);
    }
    k_att<<<R_REL*ABPR, 256, 0, stream>>>(cur1, k1W, k1b, q1, scoreS);
    k_combine1<<<(N_NODES*64/4)/256, 256, 0, stream>>>(scoreS, cur1, aggsem);

    // ---- layer 2 (h aliases cur2 slot r; k_gru's barrier makes that safe) ----
    for (int r = 0; r < R_REL; ++r){
        k_scatter<<<E_EDGES/4, 256, 0, stream>>>(ei + (size_t)r*2*E_EDGES, aggsem, agg);
        k_dense<<<DB, 256, 0, stream>>>(agg, aggsem, W2rel + r*4096, b2rel + r*64,
                                        W2root + r*4096, cur2 + r*RS);
        k_gru<<<GB, 256, 0, stream>>>(cur2 + r*RS, past2 + r*RS,
                                      g2Wi, g2Wh, g2bi, g2bh, cur2 + r*RS);
    }
    k_att<<<R_REL*ABPR, 256, 0, stream>>>(cur2, k2W, k2b, q2, scoreS + 3);
    k_combine2z<<<(N_NODES*64)/256, 256, 0, stream>>>(scoreS + 3, cur2, postW, postb, z);

    // ---- edge scores ----
    k_score<<<(R_REL*L_EDGES + 255)/256, 256, 0, stream>>>(eli, z, rel, out);
}